// Round 3
// baseline (306.168 us; speedup 1.0000x reference)
//
#include <hip/hip_runtime.h>
#include <stdint.h>

typedef float f32x16 __attribute__((ext_vector_type(16)));
typedef int v8i __attribute__((ext_vector_type(8)));
typedef int v4i __attribute__((ext_vector_type(4)));

#define BDIM 8192

// fp8 matrices stored 16B-run k-major for the K=64 scaled MFMA:
//   for byte (row, k): S = k>>6 (MFMA step), h = (k>>5)&1 (lane k-half),
//   q = (k>>4)&1 (16B half of the 32B run):
//   addr = S*524288 + h*262144 + q*131072 + row*16 + (k&15)     (1 MB per matrix)
// Segment index s = S*4 + h*2 + q (8 segments of 2KB per 128-row tile).
// 16B granularity keeps global_load_lds staging linear while ds_read_b128
// at row*16 stride is bank-conflict-free. v8i = (q0 16B, q1 16B) reproduces
// the 32B k-run byte order. Scales are uniform 1.0 (E8M0 0x7F).

// fp32 [8192,128] -> fp8 e4m3 (16B-run layout) + fp32 row sum-of-squares.
__global__ __launch_bounds__(256) void prep_kernel(const float* __restrict__ out_f,
                                                   const float* __restrict__ tgt_f,
                                                   uint8_t* __restrict__ ak,
                                                   float* __restrict__ xxyy) {
    const float* src = blockIdx.y ? tgt_f : out_f;
    uint8_t* dst = ak + (size_t)blockIdx.y * (1u << 20);
    float* nrm = xxyy + (size_t)blockIdx.y * BDIM;

    const int tid = threadIdx.x;
    const int lane = tid & 63;
    const int w = tid >> 6;
    const int jg = lane & 15;
    const int r = blockIdx.x * 16 + w * 4 + (lane >> 4);

    const float4* s4 = (const float4*)(src + (size_t)r * 128 + jg * 8);
    float4 a = s4[0], b = s4[1];

    uint32_t w0 = __builtin_amdgcn_cvt_pk_fp8_f32(a.x, a.y, 0, false);
    w0 = __builtin_amdgcn_cvt_pk_fp8_f32(a.z, a.w, w0, true);
    uint32_t w1 = __builtin_amdgcn_cvt_pk_fp8_f32(b.x, b.y, 0, false);
    w1 = __builtin_amdgcn_cvt_pk_fp8_f32(b.z, b.w, w1, true);

    *(uint2*)(dst + (jg >> 3) * 524288 + ((jg >> 2) & 1) * 262144
                  + ((jg >> 1) & 1) * 131072 + r * 16 + (jg & 1) * 8)
        = make_uint2(w0, w1);

    float sq = a.x*a.x + a.y*a.y + a.z*a.z + a.w*a.w
             + b.x*b.x + b.y*b.y + b.z*b.z + b.w*b.w;
    sq += __shfl_xor(sq, 1); sq += __shfl_xor(sq, 2);
    sq += __shfl_xor(sq, 4); sq += __shfl_xor(sq, 8);
    if (jg == 0) nrm[r] = sq;
}

__device__ __forceinline__ size_t seg_off(int s) {
    return (size_t)(s >> 2) * 524288 + (size_t)((s >> 1) & 1) * 262144
         + (size_t)(s & 1) * 131072;
}

// Stage one 128-row fp8 tile (16 KB, 16 chunks of 1KB); wave wid issues
// chunks wid*4 .. wid*4+3.
__device__ __forceinline__ void stage_tile(const uint8_t* g0, int r0,
                                           uint8_t* dst, int wid, int lane) {
    #pragma unroll
    for (int i = 0; i < 4; ++i) {
        int c = wid * 4 + i;
        int s = c >> 1, half = c & 1;
        const uint8_t* g = g0 + seg_off(s) + (size_t)(r0 + half * 64 + lane) * 16;
        uint8_t* l = dst + s * 2048 + half * 1024 + lane * 16;
        __builtin_amdgcn_global_load_lds(
            (const __attribute__((address_space(1))) unsigned int*)g,
            (__attribute__((address_space(3))) unsigned int*)l, 16, 0, 0);
    }
}

// Stage 128 f32 (512B) using waves wbase..wbase+1 (width-4 chunks).
__device__ __forceinline__ void stage_f128(const float* g, float* l,
                                           int wid, int wbase, int lane) {
    if (wid == wbase || wid == wbase + 1) {
        int half = wid - wbase;
        __builtin_amdgcn_global_load_lds(
            (const __attribute__((address_space(1))) unsigned int*)(g + half * 64 + lane),
            (__attribute__((address_space(3))) unsigned int*)(l + half * 64 + lane), 4, 0, 0);
    }
}

// dist: grid (64,16). Each block owns A rows bx*128 (+xx) and walks 4 B
// tiles by = byg*4+j with double-buffered LDS staging: issue stage(j+1)
// BEFORE compute(j) so HBM/L2 latency hides under the ~1100-cycle
// MFMA+epilogue phase (round-2 convoy effect: stage and compute phases
// never overlapped across blocks -> dist ~18us vs ~9us floor).
// 48KB LDS -> 3 blocks/CU. Plain partial store; NO agent-scope atomics.
__global__ __launch_bounds__(256, 3) void dist_kernel(const uint8_t* __restrict__ Ak,
                                                      const uint8_t* __restrict__ Bk,
                                                      const float* __restrict__ xxg,
                                                      const float* __restrict__ yyg,
                                                      float* __restrict__ partials) {
    __shared__ uint8_t sA[16384] __attribute__((aligned(16)));
    __shared__ uint8_t sB[2][16384] __attribute__((aligned(16)));
    __shared__ float xxl[128];
    __shared__ float yyl[2][128];
    __shared__ float wsum[4];

    const int tid = threadIdx.x;
    const int lane = tid & 63;
    const int wid = tid >> 6;
    const int wr = wid >> 1, wc = wid & 1;      // 2x2 wave grid, each wave 64x64
    const int bx = blockIdx.x, byg = blockIdx.y;

    // Initial stage: A tile + B tile 0 + xx + yy0.
    stage_tile(Ak, bx * 128, sA, wid, lane);
    stage_tile(Bk, byg * 512, sB[0], wid, lane);
    stage_f128(xxg + bx * 128, xxl, wid, 2, lane);
    stage_f128(yyg + byg * 512, yyl[0], wid, 0, lane);
    __syncthreads();

    const int lm = lane & 31;
    const int fh = lane >> 5;                   // k-half within a 64-k step
    const v4i* A4 = (const v4i*)sA;

    // xx fragment values: same for all 4 tiles -- hoist out of the loop.
    // ml = wr*64 + tr*32 + 8*(r>>2) + 4*fh + (r&3).
    float xv[2][16];
    #pragma unroll
    for (int tr = 0; tr < 2; ++tr)
        #pragma unroll
        for (int q = 0; q < 4; ++q) {
            float4 t = *(const float4*)&xxl[wr * 64 + tr * 32 + 8 * q + 4 * fh];
            xv[tr][q * 4 + 0] = t.x; xv[tr][q * 4 + 1] = t.y;
            xv[tr][q * 4 + 2] = t.z; xv[tr][q * 4 + 3] = t.w;
        }

    float s0 = 0.0f, s1 = 0.0f;
    float sdiag = 0.0f;

    #pragma unroll
    for (int j = 0; j < 4; ++j) {
        const int cur = j & 1;
        const int by = byg * 4 + j;

        // Issue next tile's staging first so it flies under this compute.
        if (j < 3) {
            stage_tile(Bk, (by + 1) * 128, sB[cur ^ 1], wid, lane);
            stage_f128(yyg + (by + 1) * 128, yyl[cur ^ 1], wid, 0, lane);
        }

        const v4i* B4 = (const v4i*)sB[cur];
        f32x16 acc[2][2] = {};
        #pragma unroll
        for (int S = 0; S < 2; ++S) {           // two K=64 steps
            const int sb = S * 4 + fh * 2;      // segment base (q=0)
            v4i a0l = A4[(sb + 0) * 128 + wr * 64 + lm];
            v4i a0h = A4[(sb + 1) * 128 + wr * 64 + lm];
            v4i a1l = A4[(sb + 0) * 128 + wr * 64 + 32 + lm];
            v4i a1h = A4[(sb + 1) * 128 + wr * 64 + 32 + lm];
            v4i b0l = B4[(sb + 0) * 128 + wc * 64 + lm];
            v4i b0h = B4[(sb + 1) * 128 + wc * 64 + lm];
            v4i b1l = B4[(sb + 0) * 128 + wc * 64 + 32 + lm];
            v4i b1h = B4[(sb + 1) * 128 + wc * 64 + 32 + lm];
            v8i a0 = __builtin_shufflevector(a0l, a0h, 0, 1, 2, 3, 4, 5, 6, 7);
            v8i a1 = __builtin_shufflevector(a1l, a1h, 0, 1, 2, 3, 4, 5, 6, 7);
            v8i b0 = __builtin_shufflevector(b0l, b0h, 0, 1, 2, 3, 4, 5, 6, 7);
            v8i b1 = __builtin_shufflevector(b1l, b1h, 0, 1, 2, 3, 4, 5, 6, 7);
            acc[0][0] = __builtin_amdgcn_mfma_scale_f32_32x32x64_f8f6f4(
                            a0, b0, acc[0][0], 0, 0, 0, 0x7F7F7F7F, 0, 0x7F7F7F7F);
            acc[0][1] = __builtin_amdgcn_mfma_scale_f32_32x32x64_f8f6f4(
                            a0, b1, acc[0][1], 0, 0, 0, 0x7F7F7F7F, 0, 0x7F7F7F7F);
            acc[1][0] = __builtin_amdgcn_mfma_scale_f32_32x32x64_f8f6f4(
                            a1, b0, acc[1][0], 0, 0, 0, 0x7F7F7F7F, 0, 0x7F7F7F7F);
            acc[1][1] = __builtin_amdgcn_mfma_scale_f32_32x32x64_f8f6f4(
                            a1, b1, acc[1][1], 0, 0, 0, 0x7F7F7F7F, 0, 0x7F7F7F7F);
        }

        // Epilogue: s += sqrt(|xx+yy-2c|); abs is a free v_sqrt input mod.
        #pragma unroll
        for (int tr = 0; tr < 2; ++tr)
            #pragma unroll
            for (int tc = 0; tc < 2; ++tc) {
                float yv = yyl[cur][wc * 64 + tc * 32 + lm];
                #pragma unroll
                for (int r = 0; r < 16; ++r) {
                    float d2 = fmaf(-2.0f, acc[tr][tc][r], xv[tr][r] + yv);
                    float d = __builtin_amdgcn_sqrtf(__builtin_fabsf(d2));
                    if (r & 1) s1 += d; else s0 += d;
                }
            }

        // Diagonal correction: tiles with bx == by, waves with wr == wc.
        if (bx == by && wr == wc) {
            #pragma unroll
            for (int t = 0; t < 2; ++t)
                #pragma unroll
                for (int r = 0; r < 16; ++r) {
                    int row = (r & 3) + 8 * (r >> 2) + 4 * fh;
                    if (row == lm) {
                        int idx = wr * 64 + t * 32 + row;
                        float d2 = fmaf(-2.0f, acc[t][t][r], xxl[idx] + yyl[cur][idx]);
                        sdiag += 2.0f * __builtin_amdgcn_sqrtf(__builtin_fabsf(d2));
                    }
                }
        }

        __syncthreads();   // drains this wave's vmcnt -> sB[cur^1] ready
    }

    float s = s0 + s1 - sdiag;
    #pragma unroll
    for (int off = 32; off > 0; off >>= 1) s += __shfl_down(s, off);
    if (lane == 0) wsum[wid] = s;
    __syncthreads();
    if (tid == 0) partials[byg * 64 + bx] = wsum[0] + wsum[1] + wsum[2] + wsum[3];
}

__global__ __launch_bounds__(256) void reduce_kernel(const float* __restrict__ partials,
                                                     float* __restrict__ out) {
    __shared__ float wsum[4];
    float s = 0.0f;
    #pragma unroll
    for (int i = 0; i < 4; ++i) s += partials[threadIdx.x + i * 256];
    #pragma unroll
    for (int off = 32; off > 0; off >>= 1) s += __shfl_down(s, off);
    int lane = threadIdx.x & 63, wid = threadIdx.x >> 6;
    if (lane == 0) wsum[wid] = s;
    __syncthreads();
    if (threadIdx.x == 0)
        out[0] = (wsum[0] + wsum[1] + wsum[2] + wsum[3]) * (0.1f / 8192.0f);
}

extern "C" void kernel_launch(void* const* d_in, const int* in_sizes, int n_in,
                              void* d_out, int out_size, void* d_ws, size_t ws_size,
                              hipStream_t stream) {
    const float* output = (const float*)d_in[0];
    const float* target = (const float*)d_in[1];

    uint8_t* ws = (uint8_t*)d_ws;
    uint8_t* ak      = ws;                                      // A fp8 (1MB) + B fp8 (1MB)
    float*   xxyy    = (float*)(ws + (2u << 20));               // xx (32KB) + yy (32KB)
    float*   partial = (float*)(ws + (2u << 20) + (64u << 10)); // 1024 f32

    prep_kernel<<<dim3(512, 2), 256, 0, stream>>>(output, target, ak, xxyy);
    dist_kernel<<<dim3(64, 16), 256, 0, stream>>>(ak, ak + (1u << 20),
                                                  xxyy, xxyy + BDIM, partial);
    reduce_kernel<<<1, 256, 0, stream>>>(partial, (float*)d_out);
}

// Round 4
// 105.078 us; speedup vs baseline: 2.9137x; 2.9137x over previous
//
#include <hip/hip_runtime.h>
#include <stdint.h>

typedef float f32x16 __attribute__((ext_vector_type(16)));
typedef int v8i __attribute__((ext_vector_type(8)));
typedef int v4i __attribute__((ext_vector_type(4)));

#define BDIM 8192

// fp8 matrices stored 16B-run k-major for the K=64 scaled MFMA:
//   for byte (row, k): S = k>>6 (MFMA step), h = (k>>5)&1 (lane k-half),
//   q = (k>>4)&1 (16B half of the 32B run):
//   addr = S*524288 + h*262144 + q*131072 + row*16 + (k&15)     (1 MB per matrix)
// Segment index s = S*4 + h*2 + q (8 segments of 2KB per 128-row tile).
// 16B granularity keeps global_load_lds staging linear while ds_read_b128
// at row*16 stride is bank-conflict-free. v8i = (q0 16B, q1 16B) reproduces
// the 32B k-run byte order. Scales are uniform 1.0 (E8M0 0x7F).

// fp32 [8192,128] -> fp8 e4m3 (16B-run layout) + fp32 row sum-of-squares.
__global__ __launch_bounds__(256) void prep_kernel(const float* __restrict__ out_f,
                                                   const float* __restrict__ tgt_f,
                                                   uint8_t* __restrict__ ak,
                                                   float* __restrict__ xxyy) {
    const float* src = blockIdx.y ? tgt_f : out_f;
    uint8_t* dst = ak + (size_t)blockIdx.y * (1u << 20);
    float* nrm = xxyy + (size_t)blockIdx.y * BDIM;

    const int tid = threadIdx.x;
    const int lane = tid & 63;
    const int w = tid >> 6;
    const int jg = lane & 15;
    const int r = blockIdx.x * 16 + w * 4 + (lane >> 4);

    const float4* s4 = (const float4*)(src + (size_t)r * 128 + jg * 8);
    float4 a = s4[0], b = s4[1];

    uint32_t w0 = __builtin_amdgcn_cvt_pk_fp8_f32(a.x, a.y, 0, false);
    w0 = __builtin_amdgcn_cvt_pk_fp8_f32(a.z, a.w, w0, true);
    uint32_t w1 = __builtin_amdgcn_cvt_pk_fp8_f32(b.x, b.y, 0, false);
    w1 = __builtin_amdgcn_cvt_pk_fp8_f32(b.z, b.w, w1, true);

    *(uint2*)(dst + (jg >> 3) * 524288 + ((jg >> 2) & 1) * 262144
                  + ((jg >> 1) & 1) * 131072 + r * 16 + (jg & 1) * 8)
        = make_uint2(w0, w1);

    float sq = a.x*a.x + a.y*a.y + a.z*a.z + a.w*a.w
             + b.x*b.x + b.y*b.y + b.z*b.z + b.w*b.w;
    sq += __shfl_xor(sq, 1); sq += __shfl_xor(sq, 2);
    sq += __shfl_xor(sq, 4); sq += __shfl_xor(sq, 8);
    if (jg == 0) nrm[r] = sq;
}

__device__ __forceinline__ size_t seg_off(int s) {
    return (size_t)(s >> 2) * 524288 + (size_t)((s >> 1) & 1) * 262144
         + (size_t)(s & 1) * 131072;
}

// Stage one 128-row fp8 tile (16 KB, 16 chunks of 1KB); wave wid issues
// chunks wid*4 .. wid*4+3.
__device__ __forceinline__ void stage_tile(const uint8_t* g0, int r0,
                                           uint8_t* dst, int wid, int lane) {
    #pragma unroll
    for (int i = 0; i < 4; ++i) {
        int c = wid * 4 + i;
        int s = c >> 1, half = c & 1;
        const uint8_t* g = g0 + seg_off(s) + (size_t)(r0 + half * 64 + lane) * 16;
        uint8_t* l = dst + s * 2048 + half * 1024 + lane * 16;
        __builtin_amdgcn_global_load_lds(
            (const __attribute__((address_space(1))) unsigned int*)g,
            (__attribute__((address_space(3))) unsigned int*)l, 16, 0, 0);
    }
}

// Stage 128 f32 (512B) using waves wbase..wbase+1 (width-4 chunks).
__device__ __forceinline__ void stage_f128(const float* g, float* l,
                                           int wid, int wbase, int lane) {
    if (wid == wbase || wid == wbase + 1) {
        int half = wid - wbase;
        __builtin_amdgcn_global_load_lds(
            (const __attribute__((address_space(1))) unsigned int*)(g + half * 64 + lane),
            (__attribute__((address_space(3))) unsigned int*)(l + half * 64 + lane), 4, 0, 0);
    }
}

// dist: grid (64,16). Each block stages its A tile + xx ONCE, then walks
// 4 B tiles (by = byg*4+j) single-buffered: stage B -> sync -> compute ->
// sync. Round-2 compute body verbatim (56 VGPR, no spill); round-3's
// double-buffer + hoisted-xv variant demoted arrays to scratch (451 MB
// spill writes, 267us) -- keep per-iteration state minimal, #pragma
// unroll 1 on the tile loop. LDS ~33.5KB -> 4 blocks/CU.
__global__ __launch_bounds__(256, 4) void dist_kernel(const uint8_t* __restrict__ Ak,
                                                      const uint8_t* __restrict__ Bk,
                                                      const float* __restrict__ xxg,
                                                      const float* __restrict__ yyg,
                                                      float* __restrict__ partials) {
    __shared__ uint8_t sA[16384] __attribute__((aligned(16)));
    __shared__ uint8_t sB[16384] __attribute__((aligned(16)));
    __shared__ float xxl[128];
    __shared__ float yyl[128];
    __shared__ float wsum[4];

    const int tid = threadIdx.x;
    const int lane = tid & 63;
    const int wid = tid >> 6;
    const int wr = wid >> 1, wc = wid & 1;      // 2x2 wave grid, each wave 64x64
    const int bx = blockIdx.x, byg = blockIdx.y;

    // A tile + xx staged once, reused for all 4 B tiles.
    stage_tile(Ak, bx * 128, sA, wid, lane);
    stage_f128(xxg + bx * 128, xxl, wid, 2, lane);

    const int lm = lane & 31;
    const int fh = lane >> 5;                   // k-half within a 64-k step
    const v4i* A4 = (const v4i*)sA;
    const v4i* B4 = (const v4i*)sB;

    float s0 = 0.0f, s1 = 0.0f, sdiag = 0.0f;

    #pragma unroll 1
    for (int j = 0; j < 4; ++j) {
        const int by = byg * 4 + j;
        stage_tile(Bk, by * 128, sB, wid, lane);
        stage_f128(yyg + by * 128, yyl, wid, 0, lane);
        __syncthreads();    // drains vmcnt: sA/sB/xxl/yyl ready

        f32x16 acc[2][2] = {};
        #pragma unroll
        for (int S = 0; S < 2; ++S) {           // two K=64 steps
            const int sb = S * 4 + fh * 2;      // segment base (q=0)
            v4i a0l = A4[(sb + 0) * 128 + wr * 64 + lm];
            v4i a0h = A4[(sb + 1) * 128 + wr * 64 + lm];
            v4i a1l = A4[(sb + 0) * 128 + wr * 64 + 32 + lm];
            v4i a1h = A4[(sb + 1) * 128 + wr * 64 + 32 + lm];
            v4i b0l = B4[(sb + 0) * 128 + wc * 64 + lm];
            v4i b0h = B4[(sb + 1) * 128 + wc * 64 + lm];
            v4i b1l = B4[(sb + 0) * 128 + wc * 64 + 32 + lm];
            v4i b1h = B4[(sb + 1) * 128 + wc * 64 + 32 + lm];
            v8i a0 = __builtin_shufflevector(a0l, a0h, 0, 1, 2, 3, 4, 5, 6, 7);
            v8i a1 = __builtin_shufflevector(a1l, a1h, 0, 1, 2, 3, 4, 5, 6, 7);
            v8i b0 = __builtin_shufflevector(b0l, b0h, 0, 1, 2, 3, 4, 5, 6, 7);
            v8i b1 = __builtin_shufflevector(b1l, b1h, 0, 1, 2, 3, 4, 5, 6, 7);
            acc[0][0] = __builtin_amdgcn_mfma_scale_f32_32x32x64_f8f6f4(
                            a0, b0, acc[0][0], 0, 0, 0, 0x7F7F7F7F, 0, 0x7F7F7F7F);
            acc[0][1] = __builtin_amdgcn_mfma_scale_f32_32x32x64_f8f6f4(
                            a0, b1, acc[0][1], 0, 0, 0, 0x7F7F7F7F, 0, 0x7F7F7F7F);
            acc[1][0] = __builtin_amdgcn_mfma_scale_f32_32x32x64_f8f6f4(
                            a1, b0, acc[1][0], 0, 0, 0, 0x7F7F7F7F, 0, 0x7F7F7F7F);
            acc[1][1] = __builtin_amdgcn_mfma_scale_f32_32x32x64_f8f6f4(
                            a1, b1, acc[1][1], 0, 0, 0, 0x7F7F7F7F, 0, 0x7F7F7F7F);
        }

        // Epilogue: s += sqrt(|xx+yy-2c|); abs is a free v_sqrt input mod.
        #pragma unroll
        for (int tr = 0; tr < 2; ++tr) {
            float xv[16];
            #pragma unroll
            for (int q = 0; q < 4; ++q) {
                float4 t = *(const float4*)&xxl[wr * 64 + tr * 32 + 8 * q + 4 * fh];
                xv[q * 4 + 0] = t.x; xv[q * 4 + 1] = t.y;
                xv[q * 4 + 2] = t.z; xv[q * 4 + 3] = t.w;
            }
            #pragma unroll
            for (int tc = 0; tc < 2; ++tc) {
                float yv = yyl[wc * 64 + tc * 32 + lm];
                #pragma unroll
                for (int r = 0; r < 16; ++r) {
                    float d2 = fmaf(-2.0f, acc[tr][tc][r], xv[r] + yv);
                    float d = __builtin_amdgcn_sqrtf(__builtin_fabsf(d2));
                    if (r & 1) s1 += d; else s0 += d;
                }
            }
        }

        // Diagonal correction: tiles with bx == by, waves with wr == wc.
        if (bx == by && wr == wc) {
            #pragma unroll
            for (int t = 0; t < 2; ++t)
                #pragma unroll
                for (int r = 0; r < 16; ++r) {
                    int row = (r & 3) + 8 * (r >> 2) + 4 * fh;
                    if (row == lm) {
                        int idx = wr * 64 + t * 32 + row;
                        float d2 = fmaf(-2.0f, acc[t][t][r], xxl[idx] + yyl[idx]);
                        sdiag += 2.0f * __builtin_amdgcn_sqrtf(__builtin_fabsf(d2));
                    }
                }
        }

        __syncthreads();    // all waves done reading sB before next stage
    }

    float s = s0 + s1 - sdiag;
    #pragma unroll
    for (int off = 32; off > 0; off >>= 1) s += __shfl_down(s, off);
    if (lane == 0) wsum[wid] = s;
    __syncthreads();
    if (tid == 0) partials[byg * 64 + bx] = wsum[0] + wsum[1] + wsum[2] + wsum[3];
}

__global__ __launch_bounds__(256) void reduce_kernel(const float* __restrict__ partials,
                                                     float* __restrict__ out) {
    __shared__ float wsum[4];
    float s = 0.0f;
    #pragma unroll
    for (int i = 0; i < 4; ++i) s += partials[threadIdx.x + i * 256];
    #pragma unroll
    for (int off = 32; off > 0; off >>= 1) s += __shfl_down(s, off);
    int lane = threadIdx.x & 63, wid = threadIdx.x >> 6;
    if (lane == 0) wsum[wid] = s;
    __syncthreads();
    if (threadIdx.x == 0)
        out[0] = (wsum[0] + wsum[1] + wsum[2] + wsum[3]) * (0.1f / 8192.0f);
}

extern "C" void kernel_launch(void* const* d_in, const int* in_sizes, int n_in,
                              void* d_out, int out_size, void* d_ws, size_t ws_size,
                              hipStream_t stream) {
    const float* output = (const float*)d_in[0];
    const float* target = (const float*)d_in[1];

    uint8_t* ws = (uint8_t*)d_ws;
    uint8_t* ak      = ws;                                      // A fp8 (1MB) + B fp8 (1MB)
    float*   xxyy    = (float*)(ws + (2u << 20));               // xx (32KB) + yy (32KB)
    float*   partial = (float*)(ws + (2u << 20) + (64u << 10)); // 1024 f32

    prep_kernel<<<dim3(512, 2), 256, 0, stream>>>(output, target, ak, xxyy);
    dist_kernel<<<dim3(64, 16), 256, 0, stream>>>(ak, ak + (1u << 20),
                                                  xxyy, xxyy + BDIM, partial);
    reduce_kernel<<<1, 256, 0, stream>>>(partial, (float*)d_out);
}

// Round 5
// 78.678 us; speedup vs baseline: 3.8914x; 1.3355x over previous
//
#include <hip/hip_runtime.h>
#include <stdint.h>

typedef float f32x16 __attribute__((ext_vector_type(16)));
typedef int v8i __attribute__((ext_vector_type(8)));
typedef int v4i __attribute__((ext_vector_type(4)));

#define BDIM 8192

// fp8 matrices stored 16B-run k-major for the K=64 scaled MFMA:
//   for byte (row, k): S = k>>6 (MFMA step), h = (k>>5)&1 (lane k-half),
//   q = (k>>4)&1 (16B half of the 32B run):
//   addr = S*524288 + h*262144 + q*131072 + row*16 + (k&15)     (1 MB per matrix)
// Segment index s = S*4 + h*2 + q (8 segments of 2KB per 128-row tile).
// 16B granularity keeps global_load_lds staging linear while ds_read_b128
// at row*16 stride is bank-conflict-free. v8i = (q0 16B, q1 16B) reproduces
// the 32B k-run byte order. Scales are uniform 1.0 (E8M0 0x7F).
//
// REGISTER KNIFE-EDGE (rounds 3/4 post-mortem): the dist compute body at
// __launch_bounds__(256,4) has cap 128 regs; acc uses 64 AGPR, round-2
// body uses 56 VGPR (=120, OK). Any multi-tile loop per block (extra live
// accumulators / staging state) tips it into scratch: r3 = 451 MB spill
// writes (267us), r4 = 97 MB (50us). Keep ONE tile per block.

// fp32 [8192,128] -> fp8 e4m3 (16B-run layout) + fp32 row sum-of-squares.
__global__ __launch_bounds__(256) void prep_kernel(const float* __restrict__ out_f,
                                                   const float* __restrict__ tgt_f,
                                                   uint8_t* __restrict__ ak,
                                                   float* __restrict__ xxyy) {
    const float* src = blockIdx.y ? tgt_f : out_f;
    uint8_t* dst = ak + (size_t)blockIdx.y * (1u << 20);
    float* nrm = xxyy + (size_t)blockIdx.y * BDIM;

    const int tid = threadIdx.x;
    const int lane = tid & 63;
    const int w = tid >> 6;
    const int jg = lane & 15;
    const int r = blockIdx.x * 16 + w * 4 + (lane >> 4);

    const float4* s4 = (const float4*)(src + (size_t)r * 128 + jg * 8);
    float4 a = s4[0], b = s4[1];

    uint32_t w0 = __builtin_amdgcn_cvt_pk_fp8_f32(a.x, a.y, 0, false);
    w0 = __builtin_amdgcn_cvt_pk_fp8_f32(a.z, a.w, w0, true);
    uint32_t w1 = __builtin_amdgcn_cvt_pk_fp8_f32(b.x, b.y, 0, false);
    w1 = __builtin_amdgcn_cvt_pk_fp8_f32(b.z, b.w, w1, true);

    *(uint2*)(dst + (jg >> 3) * 524288 + ((jg >> 2) & 1) * 262144
                  + ((jg >> 1) & 1) * 131072 + r * 16 + (jg & 1) * 8)
        = make_uint2(w0, w1);

    float sq = a.x*a.x + a.y*a.y + a.z*a.z + a.w*a.w
             + b.x*b.x + b.y*b.y + b.z*b.z + b.w*b.w;
    sq += __shfl_xor(sq, 1); sq += __shfl_xor(sq, 2);
    sq += __shfl_xor(sq, 4); sq += __shfl_xor(sq, 8);
    if (jg == 0) nrm[r] = sq;
}

// dist: one 128x128 tile per block (the verified round-2 structure).
// XCD-aware bijective swizzle: wgid = [by_hi(3)][bx(6)][xcd(3)] ->
// each XCD owns a contiguous stripe of 8 by-rows x 64 bx (bx fastest).
// Per-XCD working set = full A (1MB) + 8 B tiles (128KB) < 4MB L2, so
// stage reads become L2 hits (~200cy) instead of post-fill L3 (~600cy).
__global__ __launch_bounds__(256, 4) void dist_kernel(const uint8_t* __restrict__ Ak,
                                                      const uint8_t* __restrict__ Bk,
                                                      const float* __restrict__ xxg,
                                                      const float* __restrict__ yyg,
                                                      float* __restrict__ partials) {
    __shared__ uint8_t sA[16384] __attribute__((aligned(16)));
    __shared__ uint8_t sB[16384] __attribute__((aligned(16)));
    __shared__ float xxl[128];
    __shared__ float yyl[128];
    __shared__ float wsum[4];

    const int tid = threadIdx.x;
    const int lane = tid & 63;
    const int wid = tid >> 6;
    const int wr = wid >> 1, wc = wid & 1;      // 2x2 wave grid, each wave 64x64
    const int wgid = blockIdx.y * 64 + blockIdx.x;
    const int bx = (wgid >> 3) & 63;
    const int by = (wgid & 7) * 8 + (wgid >> 9);

    // Stage A/B tiles: 32 chunks of 1KB (64 lanes x 16B), 8 per wave.
    // Chunk c: mat = c>>4 (A/B), s = (c&15)>>1, half = c&1.
    {
        const int c0 = wid * 8;
        #pragma unroll
        for (int i = 0; i < 8; ++i) {
            int c = c0 + i;
            int mat = c >> 4, rem = c & 15, s = rem >> 1, half = rem & 1;
            int bidx = mat ? by : bx;
            const uint8_t* g = (mat ? Bk : Ak)
                + (s >> 2) * 524288 + ((s >> 1) & 1) * 262144 + (s & 1) * 131072
                + ((size_t)(bidx * 128 + half * 64)) * 16 + lane * 16;
            uint8_t* l = (mat ? sB : sA) + s * 2048 + half * 1024;
            __builtin_amdgcn_global_load_lds(
                (const __attribute__((address_space(1))) unsigned int*)g,
                (__attribute__((address_space(3))) unsigned int*)l, 16, 0, 0);
        }
    }
    if (tid < 128) xxl[tid] = xxg[bx * 128 + tid];
    else           yyl[tid - 128] = yyg[by * 128 + (tid - 128)];
    __syncthreads();

    const int lm = lane & 31;
    const int fh = lane >> 5;                   // k-half within a 64-k step
    const v4i* A4 = (const v4i*)sA;             // [s][row] 16B units
    const v4i* B4 = (const v4i*)sB;

    f32x16 acc[2][2] = {};
    #pragma unroll
    for (int S = 0; S < 2; ++S) {               // two K=64 steps
        const int sb = S * 4 + fh * 2;          // segment base (q=0)
        v4i a0l = A4[(sb + 0) * 128 + wr * 64 + lm];
        v4i a0h = A4[(sb + 1) * 128 + wr * 64 + lm];
        v4i a1l = A4[(sb + 0) * 128 + wr * 64 + 32 + lm];
        v4i a1h = A4[(sb + 1) * 128 + wr * 64 + 32 + lm];
        v4i b0l = B4[(sb + 0) * 128 + wc * 64 + lm];
        v4i b0h = B4[(sb + 1) * 128 + wc * 64 + lm];
        v4i b1l = B4[(sb + 0) * 128 + wc * 64 + 32 + lm];
        v4i b1h = B4[(sb + 1) * 128 + wc * 64 + 32 + lm];
        v8i a0 = __builtin_shufflevector(a0l, a0h, 0, 1, 2, 3, 4, 5, 6, 7);
        v8i a1 = __builtin_shufflevector(a1l, a1h, 0, 1, 2, 3, 4, 5, 6, 7);
        v8i b0 = __builtin_shufflevector(b0l, b0h, 0, 1, 2, 3, 4, 5, 6, 7);
        v8i b1 = __builtin_shufflevector(b1l, b1h, 0, 1, 2, 3, 4, 5, 6, 7);
        acc[0][0] = __builtin_amdgcn_mfma_scale_f32_32x32x64_f8f6f4(
                        a0, b0, acc[0][0], 0, 0, 0, 0x7F7F7F7F, 0, 0x7F7F7F7F);
        acc[0][1] = __builtin_amdgcn_mfma_scale_f32_32x32x64_f8f6f4(
                        a0, b1, acc[0][1], 0, 0, 0, 0x7F7F7F7F, 0, 0x7F7F7F7F);
        acc[1][0] = __builtin_amdgcn_mfma_scale_f32_32x32x64_f8f6f4(
                        a1, b0, acc[1][0], 0, 0, 0, 0x7F7F7F7F, 0, 0x7F7F7F7F);
        acc[1][1] = __builtin_amdgcn_mfma_scale_f32_32x32x64_f8f6f4(
                        a1, b1, acc[1][1], 0, 0, 0, 0x7F7F7F7F, 0, 0x7F7F7F7F);
    }

    // Epilogue: s += sqrt(|xx+yy-2c|); abs is a free v_sqrt input mod.
    float s0 = 0.0f, s1 = 0.0f;
    #pragma unroll
    for (int tr = 0; tr < 2; ++tr) {
        // ml = wr*64 + tr*32 + 8*(r>>2) + 4*fh + (r&3): 4 aligned float4 runs.
        float xv[16];
        #pragma unroll
        for (int q = 0; q < 4; ++q) {
            float4 t = *(const float4*)&xxl[wr * 64 + tr * 32 + 8 * q + 4 * fh];
            xv[q * 4 + 0] = t.x; xv[q * 4 + 1] = t.y;
            xv[q * 4 + 2] = t.z; xv[q * 4 + 3] = t.w;
        }
        #pragma unroll
        for (int tc = 0; tc < 2; ++tc) {
            float yv = yyl[wc * 64 + tc * 32 + lm];
            #pragma unroll
            for (int r = 0; r < 16; ++r) {
                float d2 = fmaf(-2.0f, acc[tr][tc][r], xv[r] + yv);
                float d = __builtin_amdgcn_sqrtf(__builtin_fabsf(d2));
                if (r & 1) s1 += d; else s0 += d;
            }
        }
    }
    float s = s0 + s1;

    // Diagonal correction: only 64 of 4096 blocks, only waves with wr==wc.
    if (bx == by && wr == wc) {
        #pragma unroll
        for (int t = 0; t < 2; ++t) {
            #pragma unroll
            for (int r = 0; r < 16; ++r) {
                int row = (r & 3) + 8 * (r >> 2) + 4 * fh;
                if (row == lm) {
                    int idx = wr * 64 + t * 32 + row;
                    float d2 = fmaf(-2.0f, acc[t][t][r], xxl[idx] + yyl[idx]);
                    s -= 2.0f * __builtin_amdgcn_sqrtf(__builtin_fabsf(d2));
                }
            }
        }
    }

    #pragma unroll
    for (int off = 32; off > 0; off >>= 1) s += __shfl_down(s, off);
    if (lane == 0) wsum[wid] = s;
    __syncthreads();
    if (tid == 0) partials[by * 64 + bx] = wsum[0] + wsum[1] + wsum[2] + wsum[3];
}

__global__ __launch_bounds__(256) void reduce_kernel(const float* __restrict__ partials,
                                                     float* __restrict__ out) {
    __shared__ float wsum[4];
    float s = 0.0f;
    #pragma unroll
    for (int i = 0; i < 16; ++i) s += partials[threadIdx.x + i * 256];
    #pragma unroll
    for (int off = 32; off > 0; off >>= 1) s += __shfl_down(s, off);
    int lane = threadIdx.x & 63, wid = threadIdx.x >> 6;
    if (lane == 0) wsum[wid] = s;
    __syncthreads();
    if (threadIdx.x == 0)
        out[0] = (wsum[0] + wsum[1] + wsum[2] + wsum[3]) * (0.1f / 8192.0f);
}

extern "C" void kernel_launch(void* const* d_in, const int* in_sizes, int n_in,
                              void* d_out, int out_size, void* d_ws, size_t ws_size,
                              hipStream_t stream) {
    const float* output = (const float*)d_in[0];
    const float* target = (const float*)d_in[1];

    uint8_t* ws = (uint8_t*)d_ws;
    uint8_t* ak      = ws;                                      // A fp8 (1MB) + B fp8 (1MB)
    float*   xxyy    = (float*)(ws + (2u << 20));               // xx (32KB) + yy (32KB)
    float*   partial = (float*)(ws + (2u << 20) + (64u << 10)); // 4096 f32

    prep_kernel<<<dim3(512, 2), 256, 0, stream>>>(output, target, ak, xxyy);
    dist_kernel<<<dim3(64, 64), 256, 0, stream>>>(ak, ak + (1u << 20),
                                                  xxyy, xxyy + BDIM, partial);
    reduce_kernel<<<1, 256, 0, stream>>>(partial, (float*)d_out);
}